// Round 4
// baseline (450.587 us; speedup 1.0000x reference)
//
#include <hip/hip_runtime.h>
#include <cstdint>
#include <cstddef>

#define T_STEPS 20
#define B_SZ 128
#define H_SZ 256
#define E_SZ 128
#define C_SZ 512
#define V_SZ 32000
#define G3H 768

typedef __bf16 bf16x8 __attribute__((ext_vector_type(8)));
typedef float f32x4 __attribute__((ext_vector_type(4)));
typedef unsigned short u16x8 __attribute__((ext_vector_type(8)));

#define AS1 __attribute__((address_space(1)))
#define AS3 __attribute__((address_space(3)))

__device__ __forceinline__ unsigned short f2bf(float f) {
  unsigned int u = __builtin_bit_cast(unsigned int, f);
  u += 0x7fffu + ((u >> 16) & 1u);   // round-to-nearest-even
  return (unsigned short)(u >> 16);
}

// ---------- K0: prep — Whh (i,g,o rows only; f-gate dead) -> bf16 pre-swizzled ----------
// whh_bs layout: [l][r(768 compact: 0-255=i,256-511=g,512-767=o)][k(256)] bf16,
//                element (r,k) holds Whh[origrow(r)][k ^ ((r&7)<<3)]
__global__ __launch_bounds__(256) void k_prep(const float* __restrict__ Whh_p,
    const float* __restrict__ Whh_n, unsigned short* __restrict__ whh_bs) {
  const int idx = blockIdx.x * 256 + threadIdx.x;   // 2*768*256
  const int k = idx & 255;
  const int r = (idx >> 8) % 768;
  const int l = idx / (768 * 256);
  const int gate = r >> 8;
  const int col = r & 255;
  const int row = (gate == 0 ? 0 : (gate == 1 ? 512 : 768)) + col;
  const int ksrc = (k & 7) | (((k >> 3) ^ (r & 7)) << 3);
  const float* W = l ? Whh_n : Whh_p;
  whh_bs[idx] = f2bf(W[(size_t)row * 256 + ksrc]);
}

// ---------- K1a: ctxg[l,b,g] = context[b,:] @ Wih_l[row(g),128:640] + bih + bhh ----------
__global__ __launch_bounds__(256) void k_ctx_gemm(const float* __restrict__ context,
    const float* __restrict__ Wih_p, const float* __restrict__ Wih_n,
    const float* __restrict__ bih_p, const float* __restrict__ bhh_p,
    const float* __restrict__ bih_n, const float* __restrict__ bhh_n,
    float* __restrict__ ctxg) {
  const int bid = blockIdx.x;          // 96 blocks: l(2) x btile(16) x gtile(3)
  const int l = bid / 48;
  const int bt = (bid / 3) & 15;
  const int gt = bid % 3;
  const int b0 = bt * 8;
  const int g = gt * 256 + threadIdx.x;        // compact col in [0,768)
  const int row = g + (gt > 0 ? 256 : 0);      // skip dead f-gate rows [256,512)
  __shared__ float csh[8][C_SZ];
  for (int i = threadIdx.x; i < 8 * C_SZ; i += 256)
    csh[i >> 9][i & 511] = context[(size_t)(b0 + (i >> 9)) * C_SZ + (i & 511)];
  __syncthreads();
  const float* W = (l ? Wih_n : Wih_p) + (size_t)row * 640 + E_SZ;
  float acc[8] = {};
  for (int c = 0; c < C_SZ; c += 4) {
    const float4 w = *(const float4*)(W + c);
#pragma unroll
    for (int bb = 0; bb < 8; ++bb) {
      const float4 h = *(const float4*)(&csh[bb][c]);
      acc[bb] += w.x * h.x + w.y * h.y + w.z * h.z + w.w * h.w;
    }
  }
  const float bias = l ? (bih_n[row] + bhh_n[row]) : (bih_p[row] + bhh_p[row]);
#pragma unroll
  for (int bb = 0; bb < 8; ++bb)
    ctxg[((size_t)l * B_SZ + b0 + bb) * G3H + g] = acc[bb] + bias;
}

// ---------- K1b: xg[l,r,g] = input_l[r,:] @ Wih_l[row(g),0:128] + ctxg[l, r&127, g] ----------
__global__ __launch_bounds__(256) void k_in_gemm(const float* __restrict__ inP,
    const float* __restrict__ inN,
    const float* __restrict__ Wih_p, const float* __restrict__ Wih_n,
    const float* __restrict__ ctxg, float* __restrict__ xg) {
  const int bid = blockIdx.x;          // 960 blocks: l(2) x rowtile(160) x gtile(3)
  const int l = bid / 480;
  const int rest = bid % 480;
  const int rt = rest / 3;
  const int gt = rest % 3;
  const int r0 = rt * 16;
  const int g = gt * 256 + threadIdx.x;
  const int row = g + (gt > 0 ? 256 : 0);
  __shared__ float ish[16][E_SZ];
  const float* inp = l ? inN : inP;
  for (int i = threadIdx.x; i < 16 * E_SZ; i += 256)
    ish[i >> 7][i & 127] = inp[(size_t)(r0 + (i >> 7)) * E_SZ + (i & 127)];
  __syncthreads();
  const float* W = (l ? Wih_n : Wih_p) + (size_t)row * 640;
  float acc[16] = {};
  for (int k = 0; k < E_SZ; k += 4) {
    const float4 w = *(const float4*)(W + k);
#pragma unroll
    for (int rr = 0; rr < 16; ++rr) {
      const float4 h = *(const float4*)(&ish[rr][k]);
      acc[rr] += w.x * h.x + w.y * h.y + w.z * h.z + w.w * h.w;
    }
  }
#pragma unroll
  for (int rr = 0; rr < 16; ++rr) {
    const int b = (r0 + rr) & 127;
    const float cv = ctxg[((size_t)l * B_SZ + b) * G3H + g];
    xg[((size_t)l * (T_STEPS * B_SZ) + r0 + rr) * G3H + g] = acc[rr] + cv;
  }
}

// ---------- K2: ALL 20 LSTM steps, SYNC-FREE batch-split (recurrence is batch-parallel) ----------
// grid 16 = l(2) x bt(8); block 256 = 4 waves. Block owns M=16 batches for all T steps;
// h lives in LDS across steps. Per step: stream full Whh panel (768x256 bf16 = 384 KB,
// L2-resident) through a double-buffered 64-row chunk pipe; N split across waves (16 rows each).
// No inter-block communication -> no fences, no L2 writeback/invalidate, no spin.
__global__ __launch_bounds__(256, 1) void k_steps(const unsigned short* __restrict__ whh_bs,
    const float* __restrict__ xg, const float* __restrict__ h1, const float* __restrict__ h2,
    unsigned short* __restrict__ hsb) {
  __shared__ unsigned short buf[2][64 * 256];   // 2 x 32 KB Whh chunk buffers
  __shared__ unsigned short hls[16 * 256];      // 8 KB h (bf16, k-swizzled by b&7)
  const int tid = threadIdx.x;
  const int lane = tid & 63;
  const int wave = tid >> 6;
  const int l = blockIdx.x >> 3;
  const int bt = blockIdx.x & 7;

  // h0 init: broadcast hidden row into all 16 batch rows (swizzled)
  {
    const float* h0src = l ? h2 : h1;
    const unsigned short hb = f2bf(h0src[tid]);
    const int klo = tid & 7, khi = tid >> 3;
#pragma unroll
    for (int b = 0; b < 16; ++b)
      hls[b * 256 + ((((khi) ^ (b & 7)) << 3) | klo)] = hb;
  }
  __syncthreads();

  const unsigned short* wbase = whh_bs + (size_t)l * 768 * 256;
  const int jn = wave * 16 + (lane & 15);       // n within each 64-row chunk
  const int bloc = (lane >> 4) * 4;             // output batch group (D-frag rows)

#define STAGE_W(C, BUF)                                                                  \
  {                                                                                      \
    const unsigned short* src_ = wbase + (size_t)(C) * 64 * 256 + tid * 8;               \
    unsigned short* dst_ = (unsigned short*)buf[(BUF)] + tid * 8;                        \
    _Pragma("unroll")                                                                    \
    for (int i_ = 0; i_ < 8; ++i_)                                                       \
      __builtin_amdgcn_global_load_lds((const AS1 void*)(src_ + i_ * 2048),              \
                                       (AS3 void*)(dst_ + i_ * 2048), 16, 0, 0);         \
  }

  for (int t = 0; t < T_STEPS; ++t) {
    // xg gate biases for this thread's 48 output elements -> registers
    float xgv[3][4][4];
    {
      const float* xrow = xg + ((size_t)(l * T_STEPS + t) * B_SZ + bt * 16 + bloc) * G3H;
#pragma unroll
      for (int gate = 0; gate < 3; ++gate)
#pragma unroll
        for (int cg = 0; cg < 4; ++cg)
#pragma unroll
          for (int ii = 0; ii < 3 + 1; ++ii)
            xgv[gate][cg][ii] = xrow[(size_t)ii * G3H + gate * 256 + cg * 64 + jn];
    }
    // A-frags (h) hoisted: depend on kf only
    bf16x8 af[8];
    {
      const int b = lane & 15;
#pragma unroll
      for (int kf = 0; kf < 8; ++kf) {
        const int ch = kf * 4 + (lane >> 4);
        af[kf] = __builtin_bit_cast(bf16x8, *(const u16x8*)(hls + b * 256 + ((ch ^ (b & 7)) << 3)));
      }
    }

    f32x4 acc[12];
#pragma unroll
    for (int c = 0; c < 12; ++c) acc[c] = f32x4{0.f, 0.f, 0.f, 0.f};

    STAGE_W(0, 0);
#pragma unroll
    for (int c = 0; c < 12; ++c) {
      if (c < 11) {
        STAGE_W(c + 1, (c + 1) & 1);
        asm volatile("s_waitcnt vmcnt(8)" ::: "memory");   // own stage(c) done; stage(c+1) in flight
      } else {
        asm volatile("s_waitcnt vmcnt(0)" ::: "memory");
      }
      __builtin_amdgcn_s_barrier();                        // all waves' stage(c) drained
      const unsigned short* wb = (const unsigned short*)buf[c & 1];
#pragma unroll
      for (int kf = 0; kf < 8; ++kf) {
        const int ch = kf * 4 + (lane >> 4);
        const bf16x8 bfv = __builtin_bit_cast(bf16x8,
            *(const u16x8*)(wb + jn * 256 + ((ch ^ (jn & 7)) << 3)));
        acc[c] = __builtin_amdgcn_mfma_f32_16x16x32_bf16(af[kf], bfv, acc[c], 0, 0, 0);
      }
      __builtin_amdgcn_s_barrier();                        // reads done -> buffer reusable
    }

    // epilogue: activations (f-gate dead: c0==0), write h to LDS (next step) + global (proj)
    unsigned short* hout = hsb + (size_t)(l * T_STEPS + t) * 32768;
#pragma unroll
    for (int cg = 0; cg < 4; ++cg) {
      const int j = cg * 64 + jn;
#pragma unroll
      for (int ii = 0; ii < 4; ++ii) {
        const int b = bloc + ii;
        const float gi = xgv[0][cg][ii] + acc[cg][ii];
        const float gg = xgv[1][cg][ii] + acc[4 + cg][ii];
        const float go = xgv[2][cg][ii] + acc[8 + cg][ii];
        const float cc = (1.0f / (1.0f + expf(-gi))) * tanhf(gg);
        const float h = (1.0f / (1.0f + expf(-go))) * tanhf(cc);
        const unsigned short hb = f2bf(h);
        const int kpos = (j & 7) | (((j >> 3) ^ (b & 7)) << 3);
        hout[(size_t)(bt * 16 + b) * 256 + kpos] = hb;
        hls[b * 256 + kpos] = hb;
      }
    }
    __syncthreads();   // h(t+1) visible before next step's af loads
  }
#undef STAGE_W
}

// ---------- K3: projection  out[5120,32000] = hs_bf16[5120,256] @ Wp[32000,256]^T + bp ----------
// 500 blocks x 64-col strip. Wp panel converted f32->bf16 into register B-frags once.
// A tiles (32 rows) triple-buffered via global_load_lds, counted vmcnt, raw barriers.
// Output via nontemporal stores (pure streaming, keep L2 for A/B reads).
__global__ __launch_bounds__(256, 2) void k_proj(const unsigned short* __restrict__ hsb,
    const float* __restrict__ Wp, const float* __restrict__ bias, float* __restrict__ out) {
  __shared__ unsigned short smem[3 * 32 * 256];   // 3 x 16 KB A buffers
  const int tid = threadIdx.x;
  const int lane = tid & 63;
  const int wave = tid >> 6;
  const int wgrp = wave >> 1;       // row half of 32-row tile
  const int wc = wave & 1;          // col half of 64-col strip
  const int n_base = blockIdx.x * 64 + wc * 32;
  // B panel -> registers (bf16 frags)
  bf16x8 bfr[2][8];
#pragma unroll
  for (int nt = 0; nt < 2; ++nt) {
    const int n_g = n_base + nt * 16 + (lane & 15);
    const float* src = Wp + (size_t)n_g * 256 + (lane >> 4) * 8;
#pragma unroll
    for (int kf = 0; kf < 8; ++kf) {
      const float4 a = *(const float4*)(src + kf * 32);
      const float4 b = *(const float4*)(src + kf * 32 + 4);
      u16x8 u;
      u[0] = f2bf(a.x); u[1] = f2bf(a.y); u[2] = f2bf(a.z); u[3] = f2bf(a.w);
      u[4] = f2bf(b.x); u[5] = f2bf(b.y); u[6] = f2bf(b.z); u[7] = f2bf(b.w);
      bfr[nt][kf] = __builtin_bit_cast(bf16x8, u);
    }
  }
  const float bv0 = bias[n_base + (lane & 15)];
  const float bv1 = bias[n_base + 16 + (lane & 15)];

#define STAGE_A(IT, BUF)                                                                   \
  {                                                                                        \
    const int it_ = (IT);                                                                  \
    const int l_ = it_ >= 80;                                                              \
    const int t_ = (it_ - l_ * 80) >> 2;                                                   \
    const int b0_ = (it_ & 3) * 32;                                                        \
    const unsigned short* src_ = hsb + (size_t)(l_ * T_STEPS + t_) * 32768 + b0_ * 256 + tid * 8; \
    unsigned short* dst_ = smem + (BUF) * 8192 + tid * 8;                                  \
    _Pragma("unroll")                                                                      \
    for (int i_ = 0; i_ < 4; ++i_)                                                         \
      __builtin_amdgcn_global_load_lds((const AS1 void*)(src_ + i_ * 2048),                \
                                       (AS3 void*)(dst_ + i_ * 2048), 16, 0, 0);           \
  }

  STAGE_A(0, 0);
  STAGE_A(1, 1);
  const int lr = wgrp * 16 + (lane & 15);
  for (int it = 0; it < 160; ++it) {
    __builtin_amdgcn_s_barrier();               // readers of buf[(it+2)%3] (iter it-1) done
    if (it + 2 < 160) STAGE_A(it + 2, (it + 2) % 3);
    if (it == 0) { asm volatile("s_waitcnt vmcnt(8)" ::: "memory"); }
    else         { asm volatile("s_waitcnt vmcnt(16)" ::: "memory"); }  // stage(it) done; stores + 2 stages in flight
    __builtin_amdgcn_s_barrier();               // buf[it%3] visible to all waves
    const unsigned short* sA = smem + (it % 3) * 8192;
    f32x4 acc0 = {}, acc1 = {};
#pragma unroll
    for (int kf = 0; kf < 8; ++kf) {
      const int ch = (kf * 4 + (lane >> 4)) ^ (lr & 7);
      const bf16x8 af = __builtin_bit_cast(bf16x8, *(const u16x8*)(sA + lr * 256 + (ch << 3)));
      acc0 = __builtin_amdgcn_mfma_f32_16x16x32_bf16(af, bfr[0][kf], acc0, 0, 0, 0);
      acc1 = __builtin_amdgcn_mfma_f32_16x16x32_bf16(af, bfr[1][kf], acc1, 0, 0, 0);
    }
    const size_t row0 = (size_t)it * 32 + wgrp * 16 + (lane >> 4) * 4;
    float* o0 = out + row0 * V_SZ + n_base + (lane & 15);
#pragma unroll
    for (int i = 0; i < 4; ++i) {
      __builtin_nontemporal_store(acc0[i] + bv0, &o0[(size_t)i * V_SZ]);
      __builtin_nontemporal_store(acc1[i] + bv1, &o0[(size_t)i * V_SZ + 16]);
    }
  }
#undef STAGE_A
}

extern "C" void kernel_launch(void* const* d_in, const int* in_sizes, int n_in,
                              void* d_out, int out_size, void* d_ws, size_t ws_size,
                              hipStream_t stream) {
  (void)in_sizes; (void)n_in; (void)out_size; (void)ws_size;
  const float* inputPrev = (const float*)d_in[0];
  const float* inputNext = (const float*)d_in[1];
  const float* context   = (const float*)d_in[2];
  const float* hidden1   = (const float*)d_in[3];
  const float* hidden2   = (const float*)d_in[4];
  const float* Wih_p = (const float*)d_in[5];
  const float* Whh_p = (const float*)d_in[6];
  const float* bih_p = (const float*)d_in[7];
  const float* bhh_p = (const float*)d_in[8];
  const float* Wih_n = (const float*)d_in[9];
  const float* Whh_n = (const float*)d_in[10];
  const float* bih_n = (const float*)d_in[11];
  const float* bhh_n = (const float*)d_in[12];
  const float* Wp = (const float*)d_in[13];
  const float* bp = (const float*)d_in[14];
  float* out = (float*)d_out;

  // workspace carve (16B-aligned); total ~19.9 MB
  char* ws = (char*)d_ws;
  float* xg_all        = (float*)(ws + 0);                   // [2][20][128][768] f32 = 15,728,640
  float* ctxg          = (float*)(ws + 15728640);            // [2][128][768] f32     =    786,432
  unsigned short* hsb  = (unsigned short*)(ws + 16515072);   // [2][20][128][256] bf16 swz = 2,621,440
  unsigned short* whhb = (unsigned short*)(ws + 19136512);   // [2][768][256] bf16 swz     =   786,432

  k_prep<<<1536, 256, 0, stream>>>(Whh_p, Whh_n, whhb);
  k_ctx_gemm<<<96, 256, 0, stream>>>(context, Wih_p, Wih_n, bih_p, bhh_p, bih_n, bhh_n, ctxg);
  k_in_gemm<<<960, 256, 0, stream>>>(inputPrev, inputNext, Wih_p, Wih_n, ctxg, xg_all);
  k_steps<<<16, 256, 0, stream>>>(whhb, xg_all, hidden1, hidden2, hsb);
  k_proj<<<500, 256, 0, stream>>>(hsb, Wp, bp, out);
}